// Round 1
// baseline (202.097 us; speedup 1.0000x reference)
//
#include <hip/hip_runtime.h>
#include <hip/hip_bf16.h>
#include <math.h>

#define NB 16
#define NL 1000
#define NK 17
#define NC 17
#define NH 256
#define NW 256
#define HID 64
#define IN_DIM 51          // NK * (TOPK+1)
#define PPB 15             // pairs per block (15*17 = 255 active sampling threads)
#define NPAIR (NB*NL)      // 16000

__global__ __launch_bounds__(256) void lqe_fused(
    const float* __restrict__ scores,
    const float* __restrict__ pred_poses,
    const float* __restrict__ feat,
    const float* __restrict__ w1,
    const float* __restrict__ b1,
    const float* __restrict__ w2,
    const float* __restrict__ b2,
    float* __restrict__ out)
{
    __shared__ float s_w1[HID * IN_DIM];     // 13056 B
    __shared__ float s_b1[HID];
    __shared__ float s_w2[HID];
    __shared__ float s_x[PPB][IN_DIM + 1];   // +1 pad for bank spread

    const int tid = threadIdx.x;

    // ---- stage MLP weights into LDS (coalesced) ----
    for (int i = tid; i < HID * IN_DIM; i += 256) s_w1[i] = w1[i];
    if (tid < HID) { s_b1[tid] = b1[tid]; s_w2[tid] = w2[tid]; }

    // ---- phase 1: bilinear sample + top-2 stats, one thread per (pair, k) ----
    if (tid < PPB * NK) {
        const int lp = tid / NK;
        const int k  = tid % NK;
        const int pair = blockIdx.x * PPB + lp;
        if (pair < NPAIR) {
            const int b = pair / NL;
            const float2 p = *reinterpret_cast<const float2*>(
                pred_poses + (size_t)pair * (2 * NK) + 2 * k);
            // mirror reference FP sequence exactly: grid = 2p-1; x = (g+1)*0.5*W - 0.5
            const float gx = 2.0f * p.x - 1.0f;
            const float gy = 2.0f * p.y - 1.0f;
            const float fx = (gx + 1.0f) * (0.5f * NW) - 0.5f;
            const float fy = (gy + 1.0f) * (0.5f * NH) - 0.5f;
            const float x0f = floorf(fx), y0f = floorf(fy);
            const float wx = fx - x0f,   wy = fy - y0f;
            const int ix0 = (int)x0f, iy0 = (int)y0f;
            const int ix1 = ix0 + 1,  iy1 = iy0 + 1;
            const float vx0 = (ix0 >= 0 && ix0 < NW) ? 1.f : 0.f;
            const float vx1 = (ix1 >= 0 && ix1 < NW) ? 1.f : 0.f;
            const float vy0 = (iy0 >= 0 && iy0 < NH) ? 1.f : 0.f;
            const float vy1 = (iy1 >= 0 && iy1 < NH) ? 1.f : 0.f;
            const float w00 = (1.f - wx) * (1.f - wy) * vx0 * vy0;
            const float w10 = wx * (1.f - wy) * vx1 * vy0;
            const float w01 = (1.f - wx) * wy * vx0 * vy1;
            const float w11 = wx * wy * vx1 * vy1;
            const int cx0 = min(max(ix0, 0), NW - 1), cx1 = min(max(ix1, 0), NW - 1);
            const int cy0 = min(max(iy0, 0), NH - 1), cy1 = min(max(iy1, 0), NH - 1);
            const int o00 = cy0 * NW + cx0, o10 = cy0 * NW + cx1;
            const int o01 = cy1 * NW + cx0, o11 = cy1 * NW + cx1;
            const float* fb = feat + (size_t)b * NC * NH * NW;
            float m1 = -INFINITY, m2 = -INFINITY;
            #pragma unroll
            for (int c = 0; c < NC; ++c) {
                const float* fc = fb + c * (NH * NW);
                const float v = w00 * fc[o00] + w10 * fc[o10]
                              + w01 * fc[o01] + w11 * fc[o11];
                if (v > m1)      { m2 = m1; m1 = v; }
                else if (v > m2) { m2 = v; }
            }
            s_x[lp][3 * k + 0] = m1;
            s_x[lp][3 * k + 1] = m2;
            s_x[lp][3 * k + 2] = 0.5f * (m1 + m2);
        }
    }
    __syncthreads();

    // ---- phase 2: 51->64->1 MLP, one wave per pair ----
    const int wv = tid >> 6;
    const int lane = tid & 63;
    const float vb2 = b2[0];
    for (int lp = wv; lp < PPB; lp += 4) {
        const int pair = blockIdx.x * PPB + lp;
        if (pair >= NPAIR) break;            // wave-uniform exit
        float h = s_b1[lane];
        #pragma unroll
        for (int i = 0; i < IN_DIM; ++i)
            h = fmaf(s_x[lp][i], s_w1[lane * IN_DIM + i], h);
        h = fmaxf(h, 0.f);
        float pval = h * s_w2[lane];
        #pragma unroll
        for (int off = 32; off >= 1; off >>= 1)
            pval += __shfl_xor(pval, off, 64);
        if (lane == 0) out[pair] = scores[pair] + pval + vb2;
    }
}

extern "C" void kernel_launch(void* const* d_in, const int* in_sizes, int n_in,
                              void* d_out, int out_size, void* d_ws, size_t ws_size,
                              hipStream_t stream) {
    const float* scores     = (const float*)d_in[0];
    const float* pred_poses = (const float*)d_in[1];
    const float* feat       = (const float*)d_in[2];
    const float* w1         = (const float*)d_in[3];
    const float* b1         = (const float*)d_in[4];
    const float* w2         = (const float*)d_in[5];
    const float* b2         = (const float*)d_in[6];
    float* out = (float*)d_out;

    const int grid = (NPAIR + PPB - 1) / PPB;  // 1067
    lqe_fused<<<grid, 256, 0, stream>>>(scores, pred_poses, feat,
                                        w1, b1, w2, b2, out);
}

// Round 2
// 157.611 us; speedup vs baseline: 1.2823x; 1.2823x over previous
//
#include <hip/hip_runtime.h>
#include <hip/hip_bf16.h>
#include <math.h>

#define NB 16
#define NL 1000
#define NK 17
#define NC 17
#define NH 256
#define NW 256
#define HID 64
#define IN_DIM 51          // NK * (TOPK+1)
#define PPB 15             // pairs per block (15*17 = 255 active sampling threads)
#define NPAIR (NB*NL)      // 16000
#define PADC 20            // channels padded to 20 floats (80 B, 16B-aligned)

// ---------------- transpose: feat[B,C,H,W] -> featT[B,H*W,PADC] ----------------
__global__ __launch_bounds__(256) void transpose_feat(
    const float* __restrict__ feat, float* __restrict__ featT)
{
    __shared__ float s[NC][257];            // +1 pad against bank conflicts
    const int b    = blockIdx.x >> 8;       // 16 batches x 256 chunks
    const int hw0  = (blockIdx.x & 255) * 256;
    const int tid  = threadIdx.x;
    const float* fb = feat + (size_t)b * NC * (NH * NW) + hw0;
    #pragma unroll
    for (int c = 0; c < NC; ++c)
        s[c][tid] = fb[c * (NH * NW) + tid];  // coalesced reads per plane
    __syncthreads();
    // 256 positions x 20 floats = 5120 float4, fully coalesced stores
    float4* outp = reinterpret_cast<float4*>(
        featT + ((size_t)b * (NH * NW) + hw0) * PADC);
    #pragma unroll
    for (int i = tid; i < 256 * PADC / 4; i += 256) {
        const int p = i / 5;                // 5 float4 per position
        const int j = i - 5 * p;
        float4 v;
        if (j < 4) {
            const int c = 4 * j;
            v = make_float4(s[c][p], s[c + 1][p], s[c + 2][p], s[c + 3][p]);
        } else {
            v = make_float4(s[16][p], 0.f, 0.f, 0.f);
        }
        outp[i] = v;
    }
}

// ---------------- fused sample + top2 + MLP, channels-last gather ----------------
__global__ __launch_bounds__(256) void lqe_fused_t(
    const float* __restrict__ scores,
    const float* __restrict__ pred_poses,
    const float* __restrict__ featT,
    const float* __restrict__ w1,
    const float* __restrict__ b1,
    const float* __restrict__ w2,
    const float* __restrict__ b2,
    float* __restrict__ out)
{
    __shared__ float s_w1[HID * IN_DIM];
    __shared__ float s_b1[HID];
    __shared__ float s_w2[HID];
    __shared__ float s_x[PPB][IN_DIM + 1];

    const int tid = threadIdx.x;
    for (int i = tid; i < HID * IN_DIM; i += 256) s_w1[i] = w1[i];
    if (tid < HID) { s_b1[tid] = b1[tid]; s_w2[tid] = w2[tid]; }

    if (tid < PPB * NK) {
        const int lp = tid / NK;
        const int k  = tid - lp * NK;
        const int pair = blockIdx.x * PPB + lp;
        if (pair < NPAIR) {
            const int b = pair / NL;
            const float2 p = *reinterpret_cast<const float2*>(
                pred_poses + (size_t)pair * (2 * NK) + 2 * k);
            const float gx = 2.0f * p.x - 1.0f;
            const float gy = 2.0f * p.y - 1.0f;
            const float fx = (gx + 1.0f) * (0.5f * NW) - 0.5f;
            const float fy = (gy + 1.0f) * (0.5f * NH) - 0.5f;
            const float x0f = floorf(fx), y0f = floorf(fy);
            const float wx = fx - x0f,   wy = fy - y0f;
            const int ix0 = (int)x0f, iy0 = (int)y0f;
            const int ix1 = ix0 + 1,  iy1 = iy0 + 1;
            const float vx0 = (ix0 >= 0 && ix0 < NW) ? 1.f : 0.f;
            const float vx1 = (ix1 >= 0 && ix1 < NW) ? 1.f : 0.f;
            const float vy0 = (iy0 >= 0 && iy0 < NH) ? 1.f : 0.f;
            const float vy1 = (iy1 >= 0 && iy1 < NH) ? 1.f : 0.f;
            const float w00 = (1.f - wx) * (1.f - wy) * vx0 * vy0;
            const float w10 = wx * (1.f - wy) * vx1 * vy0;
            const float w01 = (1.f - wx) * wy * vx0 * vy1;
            const float w11 = wx * wy * vx1 * vy1;
            const int cx0 = min(max(ix0, 0), NW - 1), cx1 = min(max(ix1, 0), NW - 1);
            const int cy0 = min(max(iy0, 0), NH - 1), cy1 = min(max(iy1, 0), NH - 1);
            const float* fb = featT + (size_t)b * (NH * NW) * PADC;
            const float* p00 = fb + (size_t)(cy0 * NW + cx0) * PADC;
            const float* p10 = fb + (size_t)(cy0 * NW + cx1) * PADC;
            const float* p01 = fb + (size_t)(cy1 * NW + cx0) * PADC;
            const float* p11 = fb + (size_t)(cy1 * NW + cx1) * PADC;

            float v00[NC], v10[NC], v01[NC], v11[NC];
            #pragma unroll
            for (int j = 0; j < 4; ++j) {
                *reinterpret_cast<float4*>(&v00[4 * j]) =
                    *reinterpret_cast<const float4*>(p00 + 4 * j);
                *reinterpret_cast<float4*>(&v10[4 * j]) =
                    *reinterpret_cast<const float4*>(p10 + 4 * j);
                *reinterpret_cast<float4*>(&v01[4 * j]) =
                    *reinterpret_cast<const float4*>(p01 + 4 * j);
                *reinterpret_cast<float4*>(&v11[4 * j]) =
                    *reinterpret_cast<const float4*>(p11 + 4 * j);
            }
            v00[16] = p00[16]; v10[16] = p10[16];
            v01[16] = p01[16]; v11[16] = p11[16];

            float m1 = -INFINITY, m2 = -INFINITY;
            #pragma unroll
            for (int c = 0; c < NC; ++c) {
                const float v = w00 * v00[c] + w10 * v10[c]
                              + w01 * v01[c] + w11 * v11[c];
                if (v > m1)      { m2 = m1; m1 = v; }
                else if (v > m2) { m2 = v; }
            }
            s_x[lp][3 * k + 0] = m1;
            s_x[lp][3 * k + 1] = m2;
            s_x[lp][3 * k + 2] = 0.5f * (m1 + m2);
        }
    }
    __syncthreads();

    const int wv = tid >> 6;
    const int lane = tid & 63;
    const float vb2 = b2[0];
    for (int lp = wv; lp < PPB; lp += 4) {
        const int pair = blockIdx.x * PPB + lp;
        if (pair >= NPAIR) break;
        float h = s_b1[lane];
        #pragma unroll
        for (int i = 0; i < IN_DIM; ++i)
            h = fmaf(s_x[lp][i], s_w1[lane * IN_DIM + i], h);
        h = fmaxf(h, 0.f);
        float pval = h * s_w2[lane];
        #pragma unroll
        for (int off = 32; off >= 1; off >>= 1)
            pval += __shfl_xor(pval, off, 64);
        if (lane == 0) out[pair] = scores[pair] + pval + vb2;
    }
}

// ---------------- fallback (round-1 verified): direct gather from [B,C,H,W] ----
__global__ __launch_bounds__(256) void lqe_fused_direct(
    const float* __restrict__ scores,
    const float* __restrict__ pred_poses,
    const float* __restrict__ feat,
    const float* __restrict__ w1,
    const float* __restrict__ b1,
    const float* __restrict__ w2,
    const float* __restrict__ b2,
    float* __restrict__ out)
{
    __shared__ float s_w1[HID * IN_DIM];
    __shared__ float s_b1[HID];
    __shared__ float s_w2[HID];
    __shared__ float s_x[PPB][IN_DIM + 1];

    const int tid = threadIdx.x;
    for (int i = tid; i < HID * IN_DIM; i += 256) s_w1[i] = w1[i];
    if (tid < HID) { s_b1[tid] = b1[tid]; s_w2[tid] = w2[tid]; }

    if (tid < PPB * NK) {
        const int lp = tid / NK;
        const int k  = tid - lp * NK;
        const int pair = blockIdx.x * PPB + lp;
        if (pair < NPAIR) {
            const int b = pair / NL;
            const float2 p = *reinterpret_cast<const float2*>(
                pred_poses + (size_t)pair * (2 * NK) + 2 * k);
            const float gx = 2.0f * p.x - 1.0f;
            const float gy = 2.0f * p.y - 1.0f;
            const float fx = (gx + 1.0f) * (0.5f * NW) - 0.5f;
            const float fy = (gy + 1.0f) * (0.5f * NH) - 0.5f;
            const float x0f = floorf(fx), y0f = floorf(fy);
            const float wx = fx - x0f,   wy = fy - y0f;
            const int ix0 = (int)x0f, iy0 = (int)y0f;
            const int ix1 = ix0 + 1,  iy1 = iy0 + 1;
            const float vx0 = (ix0 >= 0 && ix0 < NW) ? 1.f : 0.f;
            const float vx1 = (ix1 >= 0 && ix1 < NW) ? 1.f : 0.f;
            const float vy0 = (iy0 >= 0 && iy0 < NH) ? 1.f : 0.f;
            const float vy1 = (iy1 >= 0 && iy1 < NH) ? 1.f : 0.f;
            const float w00 = (1.f - wx) * (1.f - wy) * vx0 * vy0;
            const float w10 = wx * (1.f - wy) * vx1 * vy0;
            const float w01 = (1.f - wx) * wy * vx0 * vy1;
            const float w11 = wx * wy * vx1 * vy1;
            const int cx0 = min(max(ix0, 0), NW - 1), cx1 = min(max(ix1, 0), NW - 1);
            const int cy0 = min(max(iy0, 0), NH - 1), cy1 = min(max(iy1, 0), NH - 1);
            const int o00 = cy0 * NW + cx0, o10 = cy0 * NW + cx1;
            const int o01 = cy1 * NW + cx0, o11 = cy1 * NW + cx1;
            const float* fb = feat + (size_t)b * NC * NH * NW;
            float m1 = -INFINITY, m2 = -INFINITY;
            #pragma unroll
            for (int c = 0; c < NC; ++c) {
                const float* fc = fb + c * (NH * NW);
                const float v = w00 * fc[o00] + w10 * fc[o10]
                              + w01 * fc[o01] + w11 * fc[o11];
                if (v > m1)      { m2 = m1; m1 = v; }
                else if (v > m2) { m2 = v; }
            }
            s_x[lp][3 * k + 0] = m1;
            s_x[lp][3 * k + 1] = m2;
            s_x[lp][3 * k + 2] = 0.5f * (m1 + m2);
        }
    }
    __syncthreads();

    const int wv = tid >> 6;
    const int lane = tid & 63;
    const float vb2 = b2[0];
    for (int lp = wv; lp < PPB; lp += 4) {
        const int pair = blockIdx.x * PPB + lp;
        if (pair >= NPAIR) break;
        float h = s_b1[lane];
        #pragma unroll
        for (int i = 0; i < IN_DIM; ++i)
            h = fmaf(s_x[lp][i], s_w1[lane * IN_DIM + i], h);
        h = fmaxf(h, 0.f);
        float pval = h * s_w2[lane];
        #pragma unroll
        for (int off = 32; off >= 1; off >>= 1)
            pval += __shfl_xor(pval, off, 64);
        if (lane == 0) out[pair] = scores[pair] + pval + vb2;
    }
}

extern "C" void kernel_launch(void* const* d_in, const int* in_sizes, int n_in,
                              void* d_out, int out_size, void* d_ws, size_t ws_size,
                              hipStream_t stream) {
    const float* scores     = (const float*)d_in[0];
    const float* pred_poses = (const float*)d_in[1];
    const float* feat       = (const float*)d_in[2];
    const float* w1         = (const float*)d_in[3];
    const float* b1         = (const float*)d_in[4];
    const float* w2         = (const float*)d_in[5];
    const float* b2         = (const float*)d_in[6];
    float* out = (float*)d_out;

    const int grid = (NPAIR + PPB - 1) / PPB;  // 1067
    const size_t needT = (size_t)NB * NH * NW * PADC * sizeof(float);  // 80 MB

    if (ws_size >= needT) {
        float* featT = (float*)d_ws;
        transpose_feat<<<NB * 256, 256, 0, stream>>>(feat, featT);
        lqe_fused_t<<<grid, 256, 0, stream>>>(scores, pred_poses, featT,
                                              w1, b1, w2, b2, out);
    } else {
        lqe_fused_direct<<<grid, 256, 0, stream>>>(scores, pred_poses, feat,
                                                   w1, b1, w2, b2, out);
    }
}